// Round 2
// baseline (83815.454 us; speedup 1.0000x reference)
//
#include <hip/hip_runtime.h>

#define I_DIMM 256
#define H_DIMM 1024
#define O_DIMM 256
#define S_LENN 512
#define B_SZZ  64
#define SBB    (S_LENN*B_SZZ)      // 32768
#define KTOT   1280
#define KC     128
#define NCHUNK 10
#define NH     4                   // h-indices per block
#define NROW   16                  // gate rows per block (4 h x 4 gates)
#define NWAVE  8

__device__ __forceinline__ float sigm(float x){ return 1.f/(1.f+__expf(-x)); }
__device__ __forceinline__ float tanh_fast(float x){
  x = fminf(fmaxf(x,-15.f),15.f);
  float e = __expf(2.f*x);
  return (e-1.f)/(e+1.f);
}

// One LSTM step + fc of h_{s-1}. 256 blocks x 512 threads (8 waves).
// Block bk owns h in [4bk,4bk+4) (16 gate rows) + fc row o=bk.
// Wave w computes k-slice [c*128 + 16w, c*128 + 16w + 16) of every chunk c;
// partials combined across waves in LDS at the end.
__global__ __launch_bounds__(512) void lstm_step_kernel(
    int s,
    const float* __restrict__ X,
    const float* __restrict__ Wf, const float* __restrict__ Wi,
    const float* __restrict__ Wo, const float* __restrict__ Wc,
    const float* __restrict__ Uf, const float* __restrict__ Ui,
    const float* __restrict__ Uo, const float* __restrict__ Uc,
    const float* __restrict__ bf, const float* __restrict__ bi,
    const float* __restrict__ bo, const float* __restrict__ bc,
    const float* __restrict__ fcw, const float* __restrict__ fcb,
    const float* __restrict__ hprev, float* __restrict__ hnext,
    float* __restrict__ cbuf, float* __restrict__ out)
{
  __shared__ float s_xh[2][KC][B_SZZ];            // 64KB double-buffered xh
  __shared__ float s_red[NWAVE-1][NROW][B_SZZ];   // 28KB gate partials
  __shared__ float s_fcr[NWAVE][B_SZZ];           // 2KB  fc partials

  const int bk  = blockIdx.x;
  const int t   = threadIdx.x;
  const int b   = t & 63;
  const int wid = __builtin_amdgcn_readfirstlane(t >> 6);  // wave id 0..7
  const int kq  = wid * 16;                                // k-slice in chunk
  const bool do_g = (s < S_LENN);
  const bool do_f = (s > 0);

  const float* Wb[4] = {Wf, Wi, Wo, Wc};
  const float* Ub[4] = {Uf, Ui, Uo, Uc};

  float acc[NROW];
  #pragma unroll
  for (int r = 0; r < NROW; ++r) acc[r] = 0.f;
  float af = 0.f;

  // stage chunk 0 (k 0..127 = X part)
  #pragma unroll
  for (int m = 0; m < 16; ++m) {
    int idx = m*512 + t;
    int kk = idx >> 6, bb = idx & 63;
    s_xh[0][kk][bb] = do_g ? X[(size_t)kk*SBB + s*B_SZZ + bb] : 0.f;
  }
  __syncthreads();

  for (int c = 0; c < NCHUNK; ++c) {
    const int  k0  = c * KC;
    const bool isW = (k0 < I_DIMM);
    const bool fcc = do_f && !isW;

    // T14: issue next chunk's global loads BEFORE compute (latency hides)
    float stg[16];
    if (c + 1 < NCHUNK) {
      const int k0n = k0 + KC;
      #pragma unroll
      for (int m = 0; m < 16; ++m) {
        int idx = m*512 + t;
        int kk = idx >> 6, bb = idx & 63;
        int kg = k0n + kk;
        float v;
        if (kg < I_DIMM) v = do_g ? X[(size_t)kg*SBB + s*B_SZZ + bb] : 0.f;
        else             v = hprev[(kg - I_DIMM)*B_SZZ + bb];
        stg[m] = v;
      }
    }

    // wave-uniform weight row pointers -> SMEM s_loads
    const float* rp[NROW];
    #pragma unroll
    for (int hl = 0; hl < NH; ++hl) {
      #pragma unroll
      for (int g = 0; g < 4; ++g) {
        rp[hl*4 + g] = isW
          ? (Wb[g] + (size_t)(4*bk + hl)*I_DIMM + (k0 + kq))
          : (Ub[g] + (size_t)(4*bk + hl)*H_DIMM + (k0 - I_DIMM + kq));
      }
    }
    const int fcbase = bk*H_DIMM + (k0 - I_DIMM) + kq;

    const float (* __restrict__ xb)[B_SZZ] =
        (const float (*)[B_SZZ])s_xh[c & 1];
    #pragma unroll
    for (int j = 0; j < 16; ++j) {
      float xv = xb[kq + j][b];          // 1 LDS b32 per 16(+1) FMAs
      if (do_g) {
        #pragma unroll
        for (int r = 0; r < NROW; ++r)
          acc[r] = fmaf(rp[r][j], xv, acc[r]);   // v_fmac with SGPR weight
      }
      if (fcc) af = fmaf(fcw[fcbase + j], xv, af);
    }

    // late LDS write of the prefetched chunk (buffer c+1 was freed at the
    // barrier ending iteration c-1, so no wait needed beyond vmcnt)
    if (c + 1 < NCHUNK) {
      #pragma unroll
      for (int m = 0; m < 16; ++m) {
        int idx = m*512 + t;
        int kk = idx >> 6, bb = idx & 63;
        s_xh[(c + 1) & 1][kk][bb] = stg[m];
      }
    }
    __syncthreads();
  }

  // cross-wave combine + pointwise epilogue
  if (do_g) {
    if (wid != 0) {
      #pragma unroll
      for (int r = 0; r < NROW; ++r) s_red[wid-1][r][b] = acc[r];
    }
    if (do_f) s_fcr[wid][b] = af;
    __syncthreads();
    if (wid == 0) {
      #pragma unroll
      for (int r = 0; r < NROW; ++r) {
        float v = acc[r];
        #pragma unroll
        for (int w = 0; w < NWAVE-1; ++w) v += s_red[w][r][b];
        acc[r] = v;
      }
      #pragma unroll
      for (int hl = 0; hl < NH; ++hl) {
        const int h = 4*bk + hl;
        float zf = acc[hl*4+0] + bf[h];
        float zi = acc[hl*4+1] + bi[h];
        float zo = acc[hl*4+2] + bo[h];
        float zc = acc[hl*4+3] + bc[h];
        float fg = sigm(zf), ig = sigm(zi), og = sigm(zo);
        float ch = tanh_fast(zc);
        float cn = fg * cbuf[h*B_SZZ + b] + ig * ch;
        cbuf[h*B_SZZ + b]  = cn;
        hnext[h*B_SZZ + b] = og * tanh_fast(cn);
      }
    } else if (wid == 1 && do_f) {
      float v = fcb[bk];
      #pragma unroll
      for (int w = 0; w < NWAVE; ++w) v += s_fcr[w][b];
      out[bk*SBB + (s-1)*B_SZZ + b] = v;
    }
  } else {
    // s == S_LENN: fc-only pass for h_511
    s_fcr[wid][b] = af;
    __syncthreads();
    if (wid == 0) {
      float v = fcb[bk];
      #pragma unroll
      for (int w = 0; w < NWAVE; ++w) v += s_fcr[w][b];
      out[bk*SBB + (s-1)*B_SZZ + b] = v;
    }
  }
}

// in-place softmax over o for each (s,b) column
__global__ __launch_bounds__(256) void softmax_kernel(float* __restrict__ out)
{
  const int col = blockIdx.x*256 + threadIdx.x;
  float m = -1e30f, l = 0.f;
  for (int o = 0; o < O_DIMM; ++o) {
    float x  = out[o*SBB + col];
    float mn = fmaxf(m, x);
    l = l*__expf(m - mn) + __expf(x - mn);
    m = mn;
  }
  const float inv = 1.f / l;
  for (int o = 0; o < O_DIMM; ++o) {
    float x = out[o*SBB + col];
    out[o*SBB + col] = __expf(x - m) * inv;
  }
}

__global__ __launch_bounds__(256) void tail_kernel(
    const float* __restrict__ h, const float* __restrict__ c,
    float* __restrict__ out)
{
  const int i = blockIdx.x*256 + threadIdx.x;
  out[O_DIMM*SBB + i]                 = h[i];
  out[O_DIMM*SBB + H_DIMM*B_SZZ + i] = c[i];
}

extern "C" void kernel_launch(void* const* d_in, const int* in_sizes, int n_in,
                              void* d_out, int out_size, void* d_ws, size_t ws_size,
                              hipStream_t stream) {
  const float* X   = (const float*)d_in[0];
  const float* Wf  = (const float*)d_in[1];
  const float* Wi  = (const float*)d_in[2];
  const float* Wo  = (const float*)d_in[3];
  const float* Wc  = (const float*)d_in[4];
  const float* Uf  = (const float*)d_in[5];
  const float* Ui  = (const float*)d_in[6];
  const float* Uo  = (const float*)d_in[7];
  const float* Uc  = (const float*)d_in[8];
  const float* bf  = (const float*)d_in[9];
  const float* bi  = (const float*)d_in[10];
  const float* bo  = (const float*)d_in[11];
  const float* bc  = (const float*)d_in[12];
  const float* fcw = (const float*)d_in[13];
  const float* fcb = (const float*)d_in[14];
  float* out = (float*)d_out;

  float* ws = (float*)d_ws;
  float* h0 = ws;                          // [1024][64]
  float* h1 = ws + H_DIMM*B_SZZ;
  float* cb = ws + 2*H_DIMM*B_SZZ;

  hipMemsetAsync(h0, 0, H_DIMM*B_SZZ*sizeof(float), stream);
  hipMemsetAsync(cb, 0, H_DIMM*B_SZZ*sizeof(float), stream);

  for (int s = 0; s <= S_LENN; ++s) {
    const float* hp = (s & 1) ? h1 : h0;
    float*       hn = (s & 1) ? h0 : h1;
    lstm_step_kernel<<<256, 512, 0, stream>>>(
        s, X, Wf, Wi, Wo, Wc, Uf, Ui, Uo, Uc,
        bf, bi, bo, bc, fcw, fcb, hp, hn, cb, out);
  }
  softmax_kernel<<<SBB/256, 256, 0, stream>>>(out);
  tail_kernel<<<H_DIMM*B_SZZ/256, 256, 0, stream>>>(h0, cb, out);
}

// Round 3
// 11035.143 us; speedup vs baseline: 7.5953x; 7.5953x over previous
//
#include <hip/hip_runtime.h>

#define I_DIMM 256
#define H_DIMM 1024
#define O_DIMM 256
#define S_LENN 512
#define B_SZZ  64
#define SBB    (S_LENN*B_SZZ)      // 32768
#define KC     128
#define NCHUNK 10
#define WPAD   1284                // row stride (pad 16B): Δ4rows ≡ 16 mod 32 banks
#define NROWW  17                  // 16 gate rows + 1 fc row

typedef float f4 __attribute__((ext_vector_type(4)));

__device__ __forceinline__ float sigm(float x){ return 1.f/(1.f+__expf(-x)); }
__device__ __forceinline__ float tanh_fast(float x){
  x = fminf(fmaxf(x,-15.f),15.f);
  float e = __expf(2.f*x);
  return (e-1.f)/(e+1.f);
}

// One LSTM step + fc of h_{s-1}. 256 blocks x 512 threads (8 waves, 2/SIMD).
// Block bk owns gate rows for h in [4bk,4bk+4) + fc row o=bk.
// All weights staged row-major in LDS once per launch; xh double-buffered.
// Lane tile: 4 rows x 4 cols over the wave's 16-k slice of each 128-k chunk.
__global__ __launch_bounds__(512) void lstm_step_kernel(
    int s, const float* __restrict__ X,
    const float* __restrict__ Wf, const float* __restrict__ Wi,
    const float* __restrict__ Wo, const float* __restrict__ Wc,
    const float* __restrict__ Uf, const float* __restrict__ Ui,
    const float* __restrict__ Uo, const float* __restrict__ Uc,
    const float* __restrict__ bf, const float* __restrict__ bi,
    const float* __restrict__ bo, const float* __restrict__ bc,
    const float* __restrict__ fcw, const float* __restrict__ fcb,
    const float* __restrict__ hprev, float* __restrict__ hnext,
    float* __restrict__ cbuf, float* __restrict__ out)
{
  __shared__ __align__(16) float s_w[NROWW*WPAD];     // 87,312 B
  __shared__ __align__(16) float s_xh[2][KC][B_SZZ];  // 65,536 B  (tot 153KB)

  const int bk   = blockIdx.x;
  const int t    = threadIdx.x;
  const int lane = t & 63;
  const int wid  = __builtin_amdgcn_readfirstlane(t >> 6);  // 0..7 = k-slice
  const int bg   = lane >> 2;        // col group: cols 4bg..4bg+3
  const int rg   = lane & 3;         // row group: rows 4rg..4rg+3
  const bool do_g = (s < S_LENN);
  const bool do_f = (s > 0);

  // ---- stage weights row-major (coalesced, conflict-free), once per launch
  #pragma unroll
  for (int m = 0; m < 11; ++m) {
    int idx4 = m*512 + t;
    if (idx4 < NROWW*320) {                    // 320 float4 per 1280-row
      int row = idx4 / 320;
      int q   = idx4 - row*320;
      f4 v;
      if (row < 16) {
        int g = row & 3, h = 4*bk + (row >> 2);
        const float* wsrc = (g==0)?Wf:(g==1)?Wi:(g==2)?Wo:Wc;
        const float* usrc = (g==0)?Uf:(g==1)?Ui:(g==2)?Uo:Uc;
        v = (q < 64) ? *(const f4*)(wsrc + h*I_DIMM + 4*q)
                     : *(const f4*)(usrc + h*H_DIMM + 4*(q-64));
      } else {                                  // fc row: zeros over X-part
        v = (q < 64) ? f4{0.f,0.f,0.f,0.f}
                     : *(const f4*)(fcw + bk*H_DIMM + 4*(q-64));
      }
      *(f4*)(s_w + row*WPAD + 4*q) = v;
    }
  }

  const int c0 = do_g ? 0 : 2;   // fc-only step (s==512) never touches X

  f4 stg[4];
  // T14 split: load to regs, write LDS late
  auto stage_load = [&](int c) {
    const int k0 = c*KC;
    #pragma unroll
    for (int m = 0; m < 4; ++m) {
      int idx4 = m*512 + t;
      int kk = idx4 >> 4, bb = idx4 & 15;
      int kg = k0 + kk;
      stg[m] = (kg < I_DIMM)
        ? *(const f4*)(X + (size_t)kg*SBB + s*B_SZZ + 4*bb)
        : *(const f4*)(hprev + (kg - I_DIMM)*B_SZZ + 4*bb);
    }
  };
  auto stage_write = [&](int c) {
    #pragma unroll
    for (int m = 0; m < 4; ++m) {
      int idx4 = m*512 + t;
      int kk = idx4 >> 4, bb = idx4 & 15;
      *(f4*)(&s_xh[c & 1][kk][4*bb]) = stg[m];
    }
  };

  stage_load(c0);
  stage_write(c0);
  __syncthreads();

  f4 acc0{0,0,0,0}, acc1{0,0,0,0}, acc2{0,0,0,0}, acc3{0,0,0,0};
  f4 af{0,0,0,0};

  for (int c = c0; c < NCHUNK; ++c) {
    if (c + 1 < NCHUNK) stage_load(c + 1);
    const float* xb = &s_xh[c & 1][0][0];
    const float* wbase = s_w + 4*rg*WPAD + c*KC + wid*16;
    #pragma unroll
    for (int j = 0; j < 4; ++j) {
      const int kq = wid*16 + 4*j;
      // 4 cols x 4 k of xh (16 distinct 16B addrs/wave: all banks x2, free)
      f4 x0 = *(const f4*)(xb + (kq+0)*B_SZZ + 4*bg);
      f4 x1 = *(const f4*)(xb + (kq+1)*B_SZZ + 4*bg);
      f4 x2 = *(const f4*)(xb + (kq+2)*B_SZZ + 4*bg);
      f4 x3 = *(const f4*)(xb + (kq+3)*B_SZZ + 4*bg);
      if (do_g) {
        // 4 rows x 4 k of W (4 broadcast addrs/wave, 2-way via WPAD)
        f4 w0 = *(const f4*)(wbase + 0*WPAD + 4*j);
        f4 w1 = *(const f4*)(wbase + 1*WPAD + 4*j);
        f4 w2 = *(const f4*)(wbase + 2*WPAD + 4*j);
        f4 w3 = *(const f4*)(wbase + 3*WPAD + 4*j);
        acc0 += w0.x*x0 + w0.y*x1 + w0.z*x2 + w0.w*x3;   // 64 v_fmac
        acc1 += w1.x*x0 + w1.y*x1 + w1.z*x2 + w1.w*x3;
        acc2 += w2.x*x0 + w2.y*x1 + w2.z*x2 + w2.w*x3;
        acc3 += w3.x*x0 + w3.y*x1 + w3.z*x2 + w3.w*x3;
      }
      if (rg == j) {   // fc row: each rg-group covers one k-quad (balanced)
        f4 wf_ = *(const f4*)(s_w + 16*WPAD + c*KC + kq);
        af += wf_.x*x0 + wf_.y*x1 + wf_.z*x2 + wf_.w*x3;
      }
    }
    if (c + 1 < NCHUNK) stage_write(c + 1);
    __syncthreads();
  }

  // ---- cross-wave k-reduction via LDS overlay (xh buffers are dead now)
  float* s_red = &s_xh[0][0][0];   // [8][16][64] gate partials (32KB)
  float* s_fcr = &s_xh[1][0][0];   // [8][4][64]  fc partials
  if (do_g) {
    *(f4*)(s_red + (wid*16 + 4*rg+0)*B_SZZ + 4*bg) = acc0;
    *(f4*)(s_red + (wid*16 + 4*rg+1)*B_SZZ + 4*bg) = acc1;
    *(f4*)(s_red + (wid*16 + 4*rg+2)*B_SZZ + 4*bg) = acc2;
    *(f4*)(s_red + (wid*16 + 4*rg+3)*B_SZZ + 4*bg) = acc3;
  }
  *(f4*)(s_fcr + (wid*4 + rg)*B_SZZ + 4*bg) = af;
  __syncthreads();

  if (do_g && t < 256) {
    const int hl = t >> 6, col = t & 63;
    const int h = 4*bk + hl;
    float z[4];
    #pragma unroll
    for (int g = 0; g < 4; ++g) {
      float v = 0.f;
      #pragma unroll
      for (int ks = 0; ks < 8; ++ks)
        v += s_red[(ks*16 + 4*hl + g)*B_SZZ + col];
      z[g] = v;
    }
    float zf = z[0] + bf[h], zi = z[1] + bi[h];
    float zo = z[2] + bo[h], zc = z[3] + bc[h];
    float fg = sigm(zf), ig = sigm(zi), og = sigm(zo);
    float ch = tanh_fast(zc);
    float cn = fg*cbuf[h*B_SZZ + col] + ig*ch;
    cbuf[h*B_SZZ + col]  = cn;
    hnext[h*B_SZZ + col] = og*tanh_fast(cn);
  }
  if (do_f && t >= 448) {          // wave 7: fc output row o=bk
    const int col = t - 448;
    float v = fcb[bk];
    #pragma unroll
    for (int ks = 0; ks < 8; ++ks)
      #pragma unroll
      for (int r = 0; r < 4; ++r)
        v += s_fcr[(ks*4 + r)*B_SZZ + col];
    out[(size_t)bk*SBB + (s-1)*B_SZZ + col] = v;
  }
}

// in-place softmax over o for each (s,b) column
__global__ __launch_bounds__(256) void softmax_kernel(float* __restrict__ out)
{
  const int col = blockIdx.x*256 + threadIdx.x;
  float m = -1e30f, l = 0.f;
  for (int o = 0; o < O_DIMM; ++o) {
    float x  = out[o*SBB + col];
    float mn = fmaxf(m, x);
    l = l*__expf(m - mn) + __expf(x - mn);
    m = mn;
  }
  const float inv = 1.f / l;
  for (int o = 0; o < O_DIMM; ++o) {
    float x = out[o*SBB + col];
    out[o*SBB + col] = __expf(x - m) * inv;
  }
}

__global__ __launch_bounds__(256) void tail_kernel(
    const float* __restrict__ h, const float* __restrict__ c,
    float* __restrict__ out)
{
  const int i = blockIdx.x*256 + threadIdx.x;
  out[O_DIMM*SBB + i]                 = h[i];
  out[O_DIMM*SBB + H_DIMM*B_SZZ + i] = c[i];
}

extern "C" void kernel_launch(void* const* d_in, const int* in_sizes, int n_in,
                              void* d_out, int out_size, void* d_ws, size_t ws_size,
                              hipStream_t stream) {
  const float* X   = (const float*)d_in[0];
  const float* Wf  = (const float*)d_in[1];
  const float* Wi  = (const float*)d_in[2];
  const float* Wo  = (const float*)d_in[3];
  const float* Wc  = (const float*)d_in[4];
  const float* Uf  = (const float*)d_in[5];
  const float* Ui  = (const float*)d_in[6];
  const float* Uo  = (const float*)d_in[7];
  const float* Uc  = (const float*)d_in[8];
  const float* bf  = (const float*)d_in[9];
  const float* bi  = (const float*)d_in[10];
  const float* bo  = (const float*)d_in[11];
  const float* bc  = (const float*)d_in[12];
  const float* fcw = (const float*)d_in[13];
  const float* fcb = (const float*)d_in[14];
  float* out = (float*)d_out;

  float* ws = (float*)d_ws;
  float* h0 = ws;                          // [1024][64]
  float* h1 = ws + H_DIMM*B_SZZ;
  float* cb = ws + 2*H_DIMM*B_SZZ;

  hipMemsetAsync(h0, 0, H_DIMM*B_SZZ*sizeof(float), stream);
  hipMemsetAsync(cb, 0, H_DIMM*B_SZZ*sizeof(float), stream);

  for (int s = 0; s <= S_LENN; ++s) {
    const float* hp = (s & 1) ? h1 : h0;
    float*       hn = (s & 1) ? h0 : h1;
    lstm_step_kernel<<<256, 512, 0, stream>>>(
        s, X, Wf, Wi, Wo, Wc, Uf, Ui, Uo, Uc,
        bf, bi, bo, bc, fcw, fcb, hp, hn, cb, out);
  }
  softmax_kernel<<<SBB/256, 256, 0, stream>>>(out);
  tail_kernel<<<H_DIMM*B_SZZ/256, 256, 0, stream>>>(h0, cb, out);
}

// Round 4
// 5592.191 us; speedup vs baseline: 14.9879x; 1.9733x over previous
//
#include <hip/hip_runtime.h>

#define I_DIMM 256
#define H_DIMM 1024
#define O_DIMM 256
#define S_LENN 512
#define B_SZZ  64
#define SBB    (S_LENN*B_SZZ)      // 32768
#define NKT    40                  // k-tiles of 32 over K=1280
#define NTILE  68                  // 64 gate tiles + 4 fc tiles (64 rows each)

typedef float f32x4  __attribute__((ext_vector_type(4)));
typedef short short8 __attribute__((ext_vector_type(8)));

// ws layout (bytes):
#define OFF_ABF 0u                  // A frags: 68*40*4*64*16 = 11,141,120
#define OFF_BX  11141120u           // X frags: 512*8*4*64*16 = 16,777,216
#define OFF_HB0 27918336u           // h frags buf0: 131,072
#define OFF_HB1 28049408u           // h frags buf1: 131,072
#define OFF_C   28180480u           // c state f32: 262,144
#define OFF_HF  28442624u           // final h f32: 262,144  (total 28,704,768)

__device__ __forceinline__ float sigm(float x){ return 1.f/(1.f+__expf(-x)); }
__device__ __forceinline__ float tanh_fast(float x){
  x = fminf(fmaxf(x,-15.f),15.f);
  float e = __expf(2.f*x);
  return (e-1.f)/(e+1.f);
}
__device__ __forceinline__ unsigned short f2bf(float x){
  unsigned u = __float_as_uint(x);
  u += 0x7FFFu + ((u>>16)&1u);            // RNE
  return (unsigned short)(u>>16);
}

// ---- pack weights into A-fragment layout (once per launch) ----
// frag u = ((tile*40 + kt)*4 + mt)*64 + lane; elem j: k = kt*32+(lane>>4)*8+j,
// tile row r16 = lane&15. Gate tiles 0..63: z-row = tile*64+mt*16+r16 = 4h+g.
// fc tiles 64..67: row o = (tile-64)*64+mt*16+r16, zeros for k<256.
__global__ __launch_bounds__(256) void prep_w(
    const float* __restrict__ Wf, const float* __restrict__ Wi,
    const float* __restrict__ Wo, const float* __restrict__ Wc,
    const float* __restrict__ Uf, const float* __restrict__ Ui,
    const float* __restrict__ Uo, const float* __restrict__ Uc,
    const float* __restrict__ fcw, unsigned short* __restrict__ A_bf)
{
  int u = blockIdx.x*256 + threadIdx.x;          // 0 .. 696319
  int lane = u & 63;
  int mt   = (u >> 6) & 3;
  int kt   = (u >> 8) % NKT;
  int tile = u / (NKT*4*64);
  int r16  = lane & 15;
  int kb   = kt*32 + (lane>>4)*8;
  short8 v;
  if (tile < 64) {
    int zrow = tile*64 + mt*16 + r16;
    int h = zrow >> 2, g = zrow & 3;
    const float* Ws = (g==0)?Wf:(g==1)?Wi:(g==2)?Wo:Wc;
    const float* Us = (g==0)?Uf:(g==1)?Ui:(g==2)?Uo:Uc;
    #pragma unroll
    for (int j = 0; j < 8; ++j) {
      int k = kb + j;
      float x = (k < I_DIMM) ? Ws[h*I_DIMM + k] : Us[h*H_DIMM + (k - I_DIMM)];
      v[j] = (short)f2bf(x);
    }
  } else {
    int o = (tile-64)*64 + mt*16 + r16;
    #pragma unroll
    for (int j = 0; j < 8; ++j) {
      int k = kb + j;
      v[j] = (short)((k < I_DIMM) ? 0 : f2bf(fcw[o*H_DIMM + (k - I_DIMM)]));
    }
  }
  *(short8*)(A_bf + (size_t)u*8) = v;
}

// ---- pack X into B-fragment layout for all steps (once per launch) ----
// frag u = ((s*8 + kt)*4 + ct)*64 + lane; elem j:
//   k = kt*32+(lane>>4)*8+j, col = ct*16+(lane&15); value X[k][s][col]
__global__ __launch_bounds__(256) void prep_x(
    const float* __restrict__ X, unsigned short* __restrict__ Bx)
{
  int u = blockIdx.x*256 + threadIdx.x;          // 0 .. 1048575
  int lane = u & 63;
  int ct   = (u >> 6) & 3;
  int kt   = (u >> 8) & 7;
  int s    = u >> 11;
  int col  = ct*16 + (lane & 15);
  int kb   = kt*32 + (lane>>4)*8;
  short8 v;
  #pragma unroll
  for (int j = 0; j < 8; ++j)
    v[j] = (short)f2bf(X[(size_t)(kb + j)*SBB + s*B_SZZ + col]);
  *(short8*)(Bx + (size_t)u*8) = v;
}

// ---- one time step: 68 blocks x 512 thr (8 waves) ----
// wave w: ct = w&3 (16-col tile), half = w>>2 -> m-subtiles {2*half, 2*half+1}
__global__ __launch_bounds__(512) void lstm_step(
    int s,
    const unsigned short* __restrict__ A_bf,
    const unsigned short* __restrict__ Bx,
    const unsigned short* __restrict__ h_rd,
    unsigned short* __restrict__ h_wr,
    const float* __restrict__ bfp, const float* __restrict__ bip,
    const float* __restrict__ bop, const float* __restrict__ bcp,
    const float* __restrict__ fcb,
    float* __restrict__ cbuf, float* __restrict__ hf,
    float* __restrict__ out)
{
  const int t    = blockIdx.x;
  const int tid  = threadIdx.x;
  const int lane = tid & 63;
  const int w    = tid >> 6;
  const int ct   = w & 3;
  const int half = w >> 2;
  const int mt0  = 2*half, mt1 = 2*half + 1;

  const bool is_gate = (t < 64);
  if (is_gate) { if (s >= S_LENN) return; }
  else         { if (s == 0)      return; }

  f32x4 acc0 = {0.f,0.f,0.f,0.f}, acc1 = {0.f,0.f,0.f,0.f};
  const short8* Af = (const short8*)A_bf;
  const size_t abase = (size_t)t * NKT * 4 * 64;

  if (is_gate) {
    const short8* B0 = (const short8*)Bx + ((size_t)s*8*4*64);
    #pragma unroll
    for (int kt = 0; kt < 8; ++kt) {
      short8 b  = B0[(kt*4 + ct)*64 + lane];
      short8 a0 = Af[abase + ((size_t)kt*4 + mt0)*64 + lane];
      short8 a1 = Af[abase + ((size_t)kt*4 + mt1)*64 + lane];
      acc0 = __builtin_amdgcn_mfma_f32_16x16x32_bf16(a0, b, acc0, 0, 0, 0);
      acc1 = __builtin_amdgcn_mfma_f32_16x16x32_bf16(a1, b, acc1, 0, 0, 0);
    }
  }
  {
    const short8* Bh = (const short8*)h_rd;
    #pragma unroll
    for (int kt = 8; kt < NKT; ++kt) {
      short8 b  = Bh[((kt-8)*4 + ct)*64 + lane];
      short8 a0 = Af[abase + ((size_t)kt*4 + mt0)*64 + lane];
      short8 a1 = Af[abase + ((size_t)kt*4 + mt1)*64 + lane];
      acc0 = __builtin_amdgcn_mfma_f32_16x16x32_bf16(a0, b, acc0, 0, 0, 0);
      acc1 = __builtin_amdgcn_mfma_f32_16x16x32_bf16(a1, b, acc1, 0, 0, 0);
    }
  }

  const int col = ct*16 + (lane & 15);
  if (is_gate) {
    #pragma unroll
    for (int e = 0; e < 2; ++e) {
      f32x4 acc = e ? acc1 : acc0;
      const int mt = e ? mt1 : mt0;
      const int h  = t*16 + mt*4 + (lane >> 4);
      // C/D layout (m89-verified): col = lane&15, row = (lane>>4)*4 + reg
      // rows 4*(lane>>4)+g are the 4 gates (f,i,o,c) of h — lane-local math
      float zf = acc[0] + bfp[h];
      float zi = acc[1] + bip[h];
      float zo = acc[2] + bop[h];
      float zc = acc[3] + bcp[h];
      float fg = sigm(zf), ig = sigm(zi), og = sigm(zo);
      float ch = tanh_fast(zc);
      float cn = fg*cbuf[h*B_SZZ + col] + ig*ch;
      cbuf[h*B_SZZ + col] = cn;
      float hn = og*tanh_fast(cn);
      if (s == S_LENN-1) hf[h*B_SZZ + col] = hn;   // final h for output
      // write h in B-frag layout for next step / fc:
      //   h_kt = h>>5, k_local = h&31, lane' = 16*(k_local>>3) | (col&15),
      //   j = k_local&7
      const int kl = h & 31;
      h_wr[(((size_t)(h>>5)*4 + ct)*64 + (((kl>>3)<<4) | (lane & 15)))*8
           + (kl & 7)] = f2bf(hn);
    }
  } else {
    #pragma unroll
    for (int e = 0; e < 2; ++e) {
      f32x4 acc = e ? acc1 : acc0;
      const int mt = e ? mt1 : mt0;
      #pragma unroll
      for (int reg = 0; reg < 4; ++reg) {
        const int o = (t-64)*64 + mt*16 + 4*(lane>>4) + reg;
        out[(size_t)o*SBB + (size_t)(s-1)*B_SZZ + col] = acc[reg] + fcb[o];
      }
    }
  }
}

// in-place softmax over o for each (s,b) column
__global__ __launch_bounds__(256) void softmax_kernel(float* __restrict__ out)
{
  const int col = blockIdx.x*256 + threadIdx.x;
  float m = -1e30f, l = 0.f;
  for (int o = 0; o < O_DIMM; ++o) {
    float x  = out[(size_t)o*SBB + col];
    float mn = fmaxf(m, x);
    l = l*__expf(m - mn) + __expf(x - mn);
    m = mn;
  }
  const float inv = 1.f / l;
  for (int o = 0; o < O_DIMM; ++o) {
    float x = out[(size_t)o*SBB + col];
    out[(size_t)o*SBB + col] = __expf(x - m) * inv;
  }
}

__global__ __launch_bounds__(256) void tail_kernel(
    const float* __restrict__ h, const float* __restrict__ c,
    float* __restrict__ out)
{
  const int i = blockIdx.x*256 + threadIdx.x;     // 65536 each
  out[(size_t)O_DIMM*SBB + i]                      = h[i];
  out[(size_t)O_DIMM*SBB + H_DIMM*B_SZZ + i]       = c[i];
}

extern "C" void kernel_launch(void* const* d_in, const int* in_sizes, int n_in,
                              void* d_out, int out_size, void* d_ws, size_t ws_size,
                              hipStream_t stream) {
  const float* X   = (const float*)d_in[0];
  const float* Wf  = (const float*)d_in[1];
  const float* Wi  = (const float*)d_in[2];
  const float* Wo  = (const float*)d_in[3];
  const float* Wc  = (const float*)d_in[4];
  const float* Uf  = (const float*)d_in[5];
  const float* Ui  = (const float*)d_in[6];
  const float* Uo  = (const float*)d_in[7];
  const float* Uc  = (const float*)d_in[8];
  const float* bf  = (const float*)d_in[9];
  const float* bi  = (const float*)d_in[10];
  const float* bo  = (const float*)d_in[11];
  const float* bc  = (const float*)d_in[12];
  const float* fcw = (const float*)d_in[13];
  const float* fcb = (const float*)d_in[14];
  float* out = (float*)d_out;

  char* ws = (char*)d_ws;
  unsigned short* A_bf = (unsigned short*)(ws + OFF_ABF);
  unsigned short* Bx   = (unsigned short*)(ws + OFF_BX);
  unsigned short* hb0  = (unsigned short*)(ws + OFF_HB0);
  unsigned short* hb1  = (unsigned short*)(ws + OFF_HB1);
  float* cb = (float*)(ws + OFF_C);
  float* hf = (float*)(ws + OFF_HF);

  // ws re-poisoned 0xAA before every timed call: rebuild state every call
  hipMemsetAsync(hb0, 0, 131072, stream);          // h_{-1} = 0 (bf16 +0)
  hipMemsetAsync(cb,  0, 262144, stream);          // c_{-1} = 0
  prep_w<<<2720, 256, 0, stream>>>(Wf, Wi, Wo, Wc, Uf, Ui, Uo, Uc, fcw, A_bf);
  prep_x<<<4096, 256, 0, stream>>>(X, Bx);

  // step s: gates consume h_bf[s&1], produce h_bf[(s+1)&1];
  // fc (s>=1) consumes h_bf[s&1] = h_{s-1} -> out col s-1
  for (int s = 0; s <= S_LENN; ++s) {
    unsigned short* hrd = (s & 1) ? hb1 : hb0;
    unsigned short* hwr = (s & 1) ? hb0 : hb1;
    lstm_step<<<NTILE, 512, 0, stream>>>(
        s, A_bf, Bx, hrd, hwr, bf, bi, bo, bc, fcb, cb, hf, out);
  }
  softmax_kernel<<<SBB/256, 256, 0, stream>>>(out);
  tail_kernel<<<H_DIMM*B_SZZ/256, 256, 0, stream>>>(hf, cb, out);
}